// Round 7
// baseline (2436.596 us; speedup 1.0000x reference)
//
#include <hip/hip_runtime.h>
#include <hip/hip_bf16.h>
#include <hip/hip_cooperative_groups.h>

namespace cg = cooperative_groups;

#define HH 64
#define XDIM 896
#define FF 512
#define LL 6
#define CC 40

typedef __bf16 bf16x8 __attribute__((ext_vector_type(8)));
typedef float f32x4 __attribute__((ext_vector_type(4)));

__device__ __forceinline__ float bf2f(unsigned short u){
  union{unsigned int u; float f;} v; v.u = ((unsigned int)u)<<16; return v.f;
}
__device__ __forceinline__ unsigned short f2bf(float f){
  union{float f; unsigned int u;} v; v.f=f; unsigned int u=v.u;
  return (unsigned short)((u + 0x7fffu + ((u>>16)&1u))>>16);
}
__device__ __forceinline__ float u2f(unsigned u){
  union{unsigned u; float f;} v; v.u=u; return v.f;
}

// ============================ fallback kernels (R5, proven) ============================
__global__ void __launch_bounds__(256) k_count(const int* __restrict__ ei, int E, int* __restrict__ cnt){
  int i = blockIdx.x*blockDim.x + threadIdx.x;
  int stride = gridDim.x*blockDim.x;
  for (; i < E; i += stride) atomicAdd(&cnt[ei[E+i]], 1);
}

__global__ void __launch_bounds__(256) k_scan1(const int* __restrict__ cnt, int* __restrict__ offs,
                                               int* __restrict__ bsum, float* __restrict__ dinv, int N){
  __shared__ int s[256];
  int t=threadIdx.x, gid=blockIdx.x*256+t;
  int v = (gid<N)? cnt[gid] : 0;
  if (gid<N) dinv[gid] = rsqrtf((float)(v+1));
  s[t]=v; __syncthreads();
  for (int o=1;o<256;o<<=1){ int x=(t>=o)?s[t-o]:0; __syncthreads(); s[t]+=x; __syncthreads(); }
  if (gid<N) offs[gid]=s[t]-v;
  if (t==255) bsum[blockIdx.x]=s[t];
}

__global__ void __launch_bounds__(512) k_scan2(int* __restrict__ bsum, int nb){
  __shared__ int s[512];
  int t=threadIdx.x;
  int v=(t<nb)?bsum[t]:0; s[t]=v; __syncthreads();
  for(int o=1;o<512;o<<=1){ int x=(t>=o)?s[t-o]:0; __syncthreads(); s[t]+=x; __syncthreads(); }
  if (t<nb) bsum[t]=s[t]-v;
}

__global__ void __launch_bounds__(256) k_scan3(int* __restrict__ offs, const int* __restrict__ bsum,
                                               int* __restrict__ bcur, int N, int E){
  int gid=blockIdx.x*256+threadIdx.x;
  if (gid<N){
    int o=offs[gid]+bsum[gid>>8];
    offs[gid]=o;
    if ((gid&15)==0) bcur[gid>>4]=o;
  }
  if (gid==0) offs[N]=E;
}

__global__ void __launch_bounds__(256) k_bfill(const int* __restrict__ ei, int E,
                                               int* __restrict__ bcur, unsigned* __restrict__ tmp){
  int i = blockIdx.x*blockDim.x + threadIdx.x;
  int stride = gridDim.x*blockDim.x;
  for (; i<E; i+=stride){
    int r = ei[i], c = ei[E+i];
    int pos = atomicAdd(&bcur[c>>4], 1);
    tmp[pos] = ((unsigned)r<<4) | (unsigned)(c & 15);
  }
}

__global__ void __launch_bounds__(256) k_scatter(const unsigned* __restrict__ tmp,
                                                 const int* __restrict__ offs,
                                                 int* __restrict__ esrc, int N){
  __shared__ int cur[16];
  int b = blockIdx.x;
  int n0 = b*16;
  int n1 = n0+16; if (n1 > N) n1 = N;
  if (threadIdx.x < 16 && n0 + threadIdx.x < n1)
    cur[threadIdx.x] = offs[n0 + threadIdx.x];
  __syncthreads();
  int start = offs[n0], end = offs[n1];
  for (int i = start + threadIdx.x; i < end; i += 256){
    unsigned v = tmp[i];
    int pos = atomicAdd(&cur[v & 15u], 1);
    esrc[pos] = (int)(v >> 4);
  }
}

__global__ void __launch_bounds__(256) k_xcast(const float* __restrict__ x, unsigned short* __restrict__ X,
                                               unsigned short* __restrict__ lin, int N){
  int i = blockIdx.x*blockDim.x + threadIdx.x;
  if (i < 32) ((unsigned*)(lin + (size_t)N*64))[i] = 0u;
  int total = N*(FF/4);
  if (i >= total) return;
  int row = i/(FF/4), c4 = (i%(FF/4))*4;
  float4 v = *(const float4*)(x + (size_t)row*FF + c4);
  ushort4 o; o.x=f2bf(v.x); o.y=f2bf(v.y); o.z=f2bf(v.z); o.w=f2bf(v.w);
  *(ushort4*)(X + (size_t)row*XDIM + c4) = o;
}

struct WfA {
  const float* W[7];
  unsigned short* dst[7];
  int nt[7], nc[7];
  int off[8];
};
__global__ void __launch_bounds__(256) k_wfrag(WfA A){
  int idx = blockIdx.x*256 + threadIdx.x;
  if (idx >= A.off[7]) return;
  int seg = 0;
  while (idx >= A.off[seg+1]) ++seg;
  int li = idx - A.off[seg];
  int j = li&7, lane=(li>>3)&63, rem=li>>9;
  int ntile = A.nt[seg], ncols = A.nc[seg];
  int nt = rem % ntile, kb = rem / ntile;
  int k = kb*32 + (lane>>4)*8 + j;
  int c = nt*16 + (lane&15);
  float v = (c<ncols)? A.W[seg][(size_t)k*ncols + c] : 0.f;
  A.dst[seg][li]=f2bf(v);
}

__global__ void __launch_bounds__(256) k_gemm(const unsigned short* __restrict__ X,
                                              const unsigned short* __restrict__ Wf,
                                              const float* __restrict__ dinv,
                                              unsigned short* __restrict__ lin,
                                              int N, int nkb){
  int lane = threadIdx.x & 63, wid = threadIdx.x >> 6;
  long row0 = (long)blockIdx.x*128 + wid*32;
  int arow = lane & 15, kgrp = lane >> 4;
  long r0 = row0 + arow;      if (r0 > (long)N-1) r0 = N-1;
  long r1 = row0 + 16 + arow; if (r1 > (long)N-1) r1 = N-1;
  const unsigned short* ap0 = X + (size_t)r0*XDIM + kgrp*8;
  const unsigned short* ap1 = X + (size_t)r1*XDIM + kgrp*8;
  const unsigned short* bptr = Wf + lane*8;
  f32x4 acc00={0.f,0.f,0.f,0.f}, acc01=acc00, acc02=acc00, acc03=acc00;
  f32x4 acc10=acc00, acc11=acc00, acc12=acc00, acc13=acc00;
  for (int kb=0; kb<nkb; ++kb){
    bf16x8 a0 = *(const bf16x8*)(ap0 + (size_t)kb*32);
    bf16x8 a1 = *(const bf16x8*)(ap1 + (size_t)kb*32);
    const unsigned short* bp = bptr + (size_t)kb*2048;
    bf16x8 b0=*(const bf16x8*)bp, b1=*(const bf16x8*)(bp+512),
           b2=*(const bf16x8*)(bp+1024), b3=*(const bf16x8*)(bp+1536);
    acc00=__builtin_amdgcn_mfma_f32_16x16x32_bf16(a0,b0,acc00,0,0,0);
    acc10=__builtin_amdgcn_mfma_f32_16x16x32_bf16(a1,b0,acc10,0,0,0);
    acc01=__builtin_amdgcn_mfma_f32_16x16x32_bf16(a0,b1,acc01,0,0,0);
    acc11=__builtin_amdgcn_mfma_f32_16x16x32_bf16(a1,b1,acc11,0,0,0);
    acc02=__builtin_amdgcn_mfma_f32_16x16x32_bf16(a0,b2,acc02,0,0,0);
    acc12=__builtin_amdgcn_mfma_f32_16x16x32_bf16(a1,b2,acc12,0,0,0);
    acc03=__builtin_amdgcn_mfma_f32_16x16x32_bf16(a0,b3,acc03,0,0,0);
    acc13=__builtin_amdgcn_mfma_f32_16x16x32_bf16(a1,b3,acc13,0,0,0);
  }
  for (int j=0;j<4;++j){
    long rr = row0 + kgrp*4 + j;
    if (rr < N){
      float dv = dinv[rr];
      unsigned short* lp = lin + (size_t)rr*64 + arow;
      lp[0]  = f2bf(acc00[j]*dv);
      lp[16] = f2bf(acc01[j]*dv);
      lp[32] = f2bf(acc02[j]*dv);
      lp[48] = f2bf(acc03[j]*dv);
    }
    long rr1 = rr + 16;
    if (rr1 < N){
      float dv = dinv[rr1];
      unsigned short* lp = lin + (size_t)rr1*64 + arow;
      lp[0]  = f2bf(acc10[j]*dv);
      lp[16] = f2bf(acc11[j]*dv);
      lp[32] = f2bf(acc12[j]*dv);
      lp[48] = f2bf(acc13[j]*dv);
    }
  }
}

__global__ void __launch_bounds__(256) k_agg(const unsigned short* __restrict__ lin,
                                             const int* __restrict__ offs,
                                             const int* __restrict__ esrc,
                                             const float* __restrict__ dinv,
                                             const float* __restrict__ bias,
                                             unsigned short* __restrict__ X,
                                             int colbase, int N){
  int lane = threadIdx.x & 63, wid = threadIdx.x >> 6;
  int n = blockIdx.x*4 + wid;
  if (n >= N) return;
  int sub = lane >> 4;
  int fq  = lane & 15;
  const unsigned short* lq = lin + fq*4;
  float a0=0.f, a1=0.f, a2=0.f, a3=0.f;
  int s = offs[n], e = offs[n+1];
  int base = s;
  for (; base + 32 <= e; base += 32){
    #pragma unroll
    for (int k=0;k<8;++k){
      int sx = esrc[base + 4*k + sub];
      uint2 v = *(const uint2*)(lq + (size_t)sx*64);
      a0 += u2f(v.x<<16); a1 += u2f(v.x&0xffff0000u);
      a2 += u2f(v.y<<16); a3 += u2f(v.y&0xffff0000u);
    }
  }
  if (base < e){
    int rem = e - base;
    if (rem > 16){
      #pragma unroll
      for (int k=0;k<8;++k){
        int idx = 4*k + sub;
        int sx = esrc[base + idx];
        sx = (idx < rem) ? sx : (int)N;
        uint2 v = *(const uint2*)(lq + (size_t)sx*64);
        a0 += u2f(v.x<<16); a1 += u2f(v.x&0xffff0000u);
        a2 += u2f(v.y<<16); a3 += u2f(v.y&0xffff0000u);
      }
    } else {
      #pragma unroll
      for (int k=0;k<4;++k){
        int idx = 4*k + sub;
        int sx = esrc[base + idx];
        sx = (idx < rem) ? sx : (int)N;
        uint2 v = *(const uint2*)(lq + (size_t)sx*64);
        a0 += u2f(v.x<<16); a1 += u2f(v.x&0xffff0000u);
        a2 += u2f(v.y<<16); a3 += u2f(v.y&0xffff0000u);
      }
    }
  }
  a0 += __shfl_xor(a0,16,64); a0 += __shfl_xor(a0,32,64);
  a1 += __shfl_xor(a1,16,64); a1 += __shfl_xor(a1,32,64);
  a2 += __shfl_xor(a2,16,64); a2 += __shfl_xor(a2,32,64);
  a3 += __shfl_xor(a3,16,64); a3 += __shfl_xor(a3,32,64);
  uint2 vs = *(const uint2*)(lq + (size_t)n*64);
  a0 += u2f(vs.x<<16); a1 += u2f(vs.x&0xffff0000u);
  a2 += u2f(vs.y<<16); a3 += u2f(vs.y&0xffff0000u);
  float dv = dinv[n];
  float4 b4 = *(const float4*)(bias + fq*4);
  float h0 = fmaxf(a0*dv + b4.x, 0.f);
  float h1 = fmaxf(a1*dv + b4.y, 0.f);
  float h2 = fmaxf(a2*dv + b4.z, 0.f);
  float h3 = fmaxf(a3*dv + b4.w, 0.f);
  if (sub == 0){
    ushort4 o; o.x=f2bf(h0); o.y=f2bf(h1); o.z=f2bf(h2); o.w=f2bf(h3);
    *(ushort4*)(X + (size_t)n*XDIM + colbase + fq*4) = o;
  }
}

__global__ void __launch_bounds__(256) k_final(const unsigned short* __restrict__ X,
                                               const unsigned short* __restrict__ Wf,
                                               const float* __restrict__ blin,
                                               float* __restrict__ out, int N){
  int lane=threadIdx.x&63, wid=threadIdx.x>>6;
  long row0=(long)blockIdx.x*64 + wid*16;
  int c0=lane&15, g=lane>>4;
  long r=row0+c0; if (r > (long)N-1) r = N-1;
  const unsigned short* aptr = X + (size_t)r*XDIM + g*8;
  const unsigned short* bptr = Wf + lane*8;
  f32x4 acc0={0.f,0.f,0.f,0.f}, acc1=acc0, acc2=acc0;
  const int nkb = XDIM/32;
  for (int kb=0;kb<nkb;++kb){
    bf16x8 a=*(const bf16x8*)(aptr+(size_t)kb*32);
    const unsigned short* bp = bptr + (size_t)kb*1536;
    bf16x8 b0=*(const bf16x8*)bp, b1=*(const bf16x8*)(bp+512), b2=*(const bf16x8*)(bp+1024);
    acc0=__builtin_amdgcn_mfma_f32_16x16x32_bf16(a,b0,acc0,0,0,0);
    acc1=__builtin_amdgcn_mfma_f32_16x16x32_bf16(a,b1,acc1,0,0,0);
    acc2=__builtin_amdgcn_mfma_f32_16x16x32_bf16(a,b2,acc2,0,0,0);
  }
  float bl0 = blin[c0], bl1 = blin[16+c0];
  bool v2ok = (c0 < 8);
  float bl2 = v2ok ? blin[32+c0] : 0.f;
  for (int j=0;j<4;++j){
    long rr = row0 + g*4 + j;
    float v0 = acc0[j]+bl0, v1 = acc1[j]+bl1;
    float v2 = v2ok ? (acc2[j]+bl2) : -1e30f;
    float m = fmaxf(fmaxf(v0,v1),v2);
    m = fmaxf(m, __shfl_xor(m,1,64));
    m = fmaxf(m, __shfl_xor(m,2,64));
    m = fmaxf(m, __shfl_xor(m,4,64));
    m = fmaxf(m, __shfl_xor(m,8,64));
    float sEx = expf(v0-m)+expf(v1-m)+(v2ok?expf(v2-m):0.f);
    sEx += __shfl_xor(sEx,1,64);
    sEx += __shfl_xor(sEx,2,64);
    sEx += __shfl_xor(sEx,4,64);
    sEx += __shfl_xor(sEx,8,64);
    float lse = m + logf(sEx);
    if (rr < N){
      out[(size_t)rr*CC + c0]      = v0 - lse;
      out[(size_t)rr*CC + 16 + c0] = v1 - lse;
      if (v2ok) out[(size_t)rr*CC + 32 + c0] = v2 - lse;
    }
  }
}

// ============================ mega kernel (fully grid-stride) ============================
struct MegaP {
  const float* x; const int* ei;
  const float* W[7]; const float* bias[7];
  unsigned short* X; unsigned short* lin;
  unsigned short* Wf[7];
  float* dinv; int* cnt; int* offs; int* bcur; int* bsum; int* esrc;
  unsigned* tmp; float* out;
  int N, E, nbk, nvb;
  int wfoff[8]; int wfnt[7]; int wfnc[7];
};

#define AGG_GRP(NG, MASKED, REM) \
  _Pragma("unroll") \
  for (int k=0;k<NG;++k){ \
    int idx = 2*k + sub; \
    int sx = P.esrc[base + idx]; \
    if (MASKED) sx = (idx < (REM)) ? sx : P.N; \
    unsigned vv = *(const unsigned*)(lq2 + (size_t)sx*64); \
    a0 += u2f(vv<<16); a1 += u2f(vv & 0xffff0000u); \
  }

__global__ void __launch_bounds__(256,4) k_mega(MegaP P){
  cg::grid_group grid = cg::this_grid();
  __shared__ int sh[1024];
  const int t = threadIdx.x;
  const int b = blockIdx.x;
  const int G = gridDim.x;
  const int lane = t & 63, wid = t >> 6;
  const int N = P.N, E = P.E;

  // ---- P0: zero cnt, zero lin row N, xcast, wfrag ----
  for (int i = b*256+t; i < N; i += G*256) P.cnt[i] = 0;
  if (b==0 && t<32) ((unsigned*)(P.lin + (size_t)N*64))[t] = 0u;
  {
    int total = N*(FF/4);
    for (int i = b*256+t; i < total; i += G*256){
      int row = i/(FF/4), c4 = (i%(FF/4))*4;
      float4 v = *(const float4*)(P.x + (size_t)row*FF + c4);
      ushort4 o; o.x=f2bf(v.x); o.y=f2bf(v.y); o.z=f2bf(v.z); o.w=f2bf(v.w);
      *(ushort4*)(P.X + (size_t)row*XDIM + c4) = o;
    }
  }
  for (int idx = b*256+t; idx < P.wfoff[7]; idx += G*256){
    int seg = 0;
    while (idx >= P.wfoff[seg+1]) ++seg;
    int li = idx - P.wfoff[seg];
    int j = li&7, ln=(li>>3)&63, rem=li>>9;
    int ntile = P.wfnt[seg], ncols = P.wfnc[seg];
    int nt = rem % ntile, kb = rem / ntile;
    int k = kb*32 + (ln>>4)*8 + j;
    int c = nt*16 + (ln&15);
    float v = (c<ncols)? P.W[seg][(size_t)k*ncols + c] : 0.f;
    P.Wf[seg][li] = f2bf(v);
  }
  grid.sync();

  // ---- P1: degree count ----
  for (int i = b*256+t; i < E; i += G*256) atomicAdd(&P.cnt[P.ei[E+i]], 1);
  grid.sync();

  // ---- P2: per-256-chunk scan + dinv (grid-stride over chunks) ----
  for (int cb = b; cb < P.nvb; cb += G){
    int gid = cb*256 + t;
    int v = (gid<N)? P.cnt[gid] : 0;
    if (gid<N) P.dinv[gid] = rsqrtf((float)(v+1));
    __syncthreads();
    sh[t]=v; __syncthreads();
    for (int o=1;o<256;o<<=1){ int x=(t>=o)?sh[t-o]:0; __syncthreads(); sh[t]+=x; __syncthreads(); }
    if (gid<N) P.offs[gid]=sh[t]-v;
    if (t==255) P.bsum[cb]=sh[t];
  }
  grid.sync();

  // ---- P3: scan of chunk sums (block 0, 512 slots) ----
  if (b==0){
    int i0=t, i1=t+256;
    int v0=(i0<P.nvb)?P.bsum[i0]:0, v1=(i1<P.nvb)?P.bsum[i1]:0;
    int* A = sh; int* Bb = sh+512;
    A[i0]=v0; A[i1]=v1; __syncthreads();
    int* src=A; int* dst=Bb;
    for (int o=1;o<512;o<<=1){
      dst[i0]=src[i0]+((i0>=o)?src[i0-o]:0);
      dst[i1]=src[i1]+((i1>=o)?src[i1-o]:0);
      __syncthreads();
      int* tp=src; src=dst; dst=tp;
    }
    if (i0<P.nvb) P.bsum[i0]=src[i0]-v0;
    if (i1<P.nvb) P.bsum[i1]=src[i1]-v1;
  }
  grid.sync();

  // ---- P4: finalize offs + bucket cursors ----
  for (int gid=b*256+t; gid<N; gid+=G*256){
    int o=P.offs[gid]+P.bsum[gid>>8];
    P.offs[gid]=o;
    if ((gid&15)==0) P.bcur[gid>>4]=o;
  }
  if (b==0 && t==0) P.offs[N]=E;
  grid.sync();

  // ---- P5: bucket-partition edges ----
  for (int i=b*256+t; i<E; i+=G*256){
    int r=P.ei[i], c=P.ei[E+i];
    int pos=atomicAdd(&P.bcur[c>>4],1);
    P.tmp[pos]=((unsigned)r<<4)|(unsigned)(c&15);
  }
  grid.sync();

  // ---- P6: within-bucket scatter, LDS cursors ----
  for (int vb=b; vb<P.nbk; vb+=G){
    int n0=vb*16, n1=n0+16; if (n1>N) n1=N;
    __syncthreads();
    if (t<16 && n0+t<n1) sh[t]=P.offs[n0+t];
    __syncthreads();
    int start=P.offs[n0], end=P.offs[n1];
    for (int i=start+t; i<end; i+=256){
      unsigned v=P.tmp[i];
      int pos=atomicAdd(&sh[v&15u],1);
      P.esrc[pos]=(int)(v>>4);
    }
  }
  grid.sync();

  // ---- layers: gemm -> sync -> agg -> sync ----
  for (int L=0; L<LL; ++L){
    const int nkb = (FF + HH*L) >> 5;
    const unsigned short* Wfp = P.Wf[L];
    for (long rb = (long)b*128; rb < N; rb += (long)G*128){
      long row0 = rb + wid*32;
      int arow = lane & 15, kgrp = lane >> 4;
      long r0 = row0 + arow;      if (r0 > (long)N-1) r0 = N-1;
      long r1 = row0 + 16 + arow; if (r1 > (long)N-1) r1 = N-1;
      const unsigned short* ap0 = P.X + (size_t)r0*XDIM + kgrp*8;
      const unsigned short* ap1 = P.X + (size_t)r1*XDIM + kgrp*8;
      const unsigned short* bptr = Wfp + lane*8;
      f32x4 acc00={0.f,0.f,0.f,0.f}, acc01=acc00, acc02=acc00, acc03=acc00;
      f32x4 acc10=acc00, acc11=acc00, acc12=acc00, acc13=acc00;
      for (int kb=0; kb<nkb; ++kb){
        bf16x8 a0 = *(const bf16x8*)(ap0 + (size_t)kb*32);
        bf16x8 a1 = *(const bf16x8*)(ap1 + (size_t)kb*32);
        const unsigned short* bp = bptr + (size_t)kb*2048;
        bf16x8 b0=*(const bf16x8*)bp, b1=*(const bf16x8*)(bp+512),
               b2=*(const bf16x8*)(bp+1024), b3=*(const bf16x8*)(bp+1536);
        acc00=__builtin_amdgcn_mfma_f32_16x16x32_bf16(a0,b0,acc00,0,0,0);
        acc10=__builtin_amdgcn_mfma_f32_16x16x32_bf16(a1,b0,acc10,0,0,0);
        acc01=__builtin_amdgcn_mfma_f32_16x16x32_bf16(a0,b1,acc01,0,0,0);
        acc11=__builtin_amdgcn_mfma_f32_16x16x32_bf16(a1,b1,acc11,0,0,0);
        acc02=__builtin_amdgcn_mfma_f32_16x16x32_bf16(a0,b2,acc02,0,0,0);
        acc12=__builtin_amdgcn_mfma_f32_16x16x32_bf16(a1,b2,acc12,0,0,0);
        acc03=__builtin_amdgcn_mfma_f32_16x16x32_bf16(a0,b3,acc03,0,0,0);
        acc13=__builtin_amdgcn_mfma_f32_16x16x32_bf16(a1,b3,acc13,0,0,0);
      }
      for (int j=0;j<4;++j){
        long rr = row0 + kgrp*4 + j;
        if (rr < N){
          float dv = P.dinv[rr];
          unsigned short* lp = P.lin + (size_t)rr*64 + arow;
          lp[0]  = f2bf(acc00[j]*dv);
          lp[16] = f2bf(acc01[j]*dv);
          lp[32] = f2bf(acc02[j]*dv);
          lp[48] = f2bf(acc03[j]*dv);
        }
        long rr1 = rr + 16;
        if (rr1 < N){
          float dv = P.dinv[rr1];
          unsigned short* lp = P.lin + (size_t)rr1*64 + arow;
          lp[0]  = f2bf(acc10[j]*dv);
          lp[16] = f2bf(acc11[j]*dv);
          lp[32] = f2bf(acc12[j]*dv);
          lp[48] = f2bf(acc13[j]*dv);
        }
      }
    }
    grid.sync();
    {
      const float* bias = P.bias[L];
      const int colbase = FF + HH*L;
      int sub = lane >> 5, fq = lane & 31;
      const unsigned short* lq2 = P.lin + fq*2;
      for (int n = b*4 + wid; n < N; n += G*4){
        float a0=0.f, a1=0.f;
        int s=P.offs[n], e=P.offs[n+1];
        int base=s;
        for (; base+32<=e; base+=32){ AGG_GRP(16, false, 0) }
        if (base<e){
          int rem=e-base;
          if (rem<=8)      { AGG_GRP(4,  true, rem) }
          else if (rem<=16){ AGG_GRP(8,  true, rem) }
          else             { AGG_GRP(16, true, rem) }
        }
        a0 += __shfl_xor(a0,32,64);
        a1 += __shfl_xor(a1,32,64);
        unsigned vs = *(const unsigned*)(lq2 + (size_t)n*64);
        a0 += u2f(vs<<16); a1 += u2f(vs&0xffff0000u);
        float dv = P.dinv[n];
        float2 b2 = *(const float2*)(bias + fq*2);
        float h0 = fmaxf(a0*dv + b2.x, 0.f);
        float h1 = fmaxf(a1*dv + b2.y, 0.f);
        if (sub == 0){
          ushort2 o; o.x=f2bf(h0); o.y=f2bf(h1);
          *(ushort2*)(P.X + (size_t)n*XDIM + colbase + fq*2) = o;
        }
      }
    }
    grid.sync();
  }

  // ---- final: logits + log_softmax (grid-stride, 64 rows/block-iter) ----
  {
    const float* blin = P.bias[6];
    const unsigned short* WfF = P.Wf[6];
    int c0=lane&15, g=lane>>4;
    for (long fb = (long)b*64; fb < N; fb += (long)G*64){
      long row0 = fb + wid*16;
      long r = row0+c0; if (r > (long)N-1) r = N-1;
      const unsigned short* aptr = P.X + (size_t)r*XDIM + g*8;
      const unsigned short* bptr = WfF + lane*8;
      f32x4 acc0={0.f,0.f,0.f,0.f}, acc1=acc0, acc2=acc0;
      const int nkb = XDIM/32;
      for (int kb=0;kb<nkb;++kb){
        bf16x8 a=*(const bf16x8*)(aptr+(size_t)kb*32);
        const unsigned short* bp = bptr + (size_t)kb*1536;
        bf16x8 b0=*(const bf16x8*)bp, b1=*(const bf16x8*)(bp+512), b2=*(const bf16x8*)(bp+1024);
        acc0=__builtin_amdgcn_mfma_f32_16x16x32_bf16(a,b0,acc0,0,0,0);
        acc1=__builtin_amdgcn_mfma_f32_16x16x32_bf16(a,b1,acc1,0,0,0);
        acc2=__builtin_amdgcn_mfma_f32_16x16x32_bf16(a,b2,acc2,0,0,0);
      }
      float bl0 = blin[c0], bl1 = blin[16+c0];
      bool v2ok = (c0 < 8);
      float bl2 = v2ok ? blin[32+c0] : 0.f;
      for (int j=0;j<4;++j){
        long rr = row0 + g*4 + j;
        float v0 = acc0[j]+bl0, v1 = acc1[j]+bl1;
        float v2 = v2ok ? (acc2[j]+bl2) : -1e30f;
        float m = fmaxf(fmaxf(v0,v1),v2);
        m = fmaxf(m, __shfl_xor(m,1,64));
        m = fmaxf(m, __shfl_xor(m,2,64));
        m = fmaxf(m, __shfl_xor(m,4,64));
        m = fmaxf(m, __shfl_xor(m,8,64));
        float sEx = expf(v0-m)+expf(v1-m)+(v2ok?expf(v2-m):0.f);
        sEx += __shfl_xor(sEx,1,64);
        sEx += __shfl_xor(sEx,2,64);
        sEx += __shfl_xor(sEx,4,64);
        sEx += __shfl_xor(sEx,8,64);
        float lse = m + logf(sEx);
        if (rr < N){
          P.out[(size_t)rr*CC + c0]      = v0 - lse;
          P.out[(size_t)rr*CC + 16 + c0] = v1 - lse;
          if (v2ok) P.out[(size_t)rr*CC + 32 + c0] = v2 - lse;
        }
      }
    }
  }
}

extern "C" void kernel_launch(void* const* d_in, const int* in_sizes, int n_in,
                              void* d_out, int out_size, void* d_ws, size_t ws_size,
                              hipStream_t stream){
  const float* x = (const float*)d_in[0];
  const int* ei = (const int*)d_in[1];
  const int N = in_sizes[0]/FF;
  const int E = in_sizes[1]/2;
  const int nbk = (N+15)/16;

  char* p = (char*)d_ws;
  auto alloc = [&](size_t bb)->char*{ char* r=p; p += (bb+255)&~(size_t)255; return r; };
  unsigned short* X   = (unsigned short*)alloc((size_t)N*XDIM*2);
  unsigned short* lin = (unsigned short*)alloc((size_t)(N+1)*64*2);
  unsigned* tmp = (unsigned*)lin;
  unsigned short* WfL[LL+1];
  for (int i=0;i<LL;i++){ int d=FF+HH*i; WfL[i]=(unsigned short*)alloc((size_t)d*64*2); }
  WfL[LL] = (unsigned short*)alloc((size_t)XDIM*48*2);
  float* dinv = (float*)alloc((size_t)N*4);
  int* cnt    = (int*)alloc((size_t)N*4);
  int* offs   = (int*)alloc((size_t)(N+1)*4);
  int* bcur   = (int*)alloc((size_t)nbk*4);
  int* bsum   = (int*)alloc(512*4);
  int* esrc   = (int*)alloc((size_t)(E+64)*4);

  MegaP P;
  P.x = x; P.ei = ei;
  for (int i=0;i<LL;i++){ P.W[i]=(const float*)d_in[2+2*i]; P.bias[i]=(const float*)d_in[3+2*i]; }
  P.W[LL]=(const float*)d_in[2+2*LL]; P.bias[LL]=(const float*)d_in[3+2*LL];
  P.X=X; P.lin=lin;
  for (int i=0;i<=LL;i++) P.Wf[i]=WfL[i];
  P.dinv=dinv; P.cnt=cnt; P.offs=offs; P.bcur=bcur; P.bsum=bsum; P.esrc=esrc;
  P.tmp=tmp; P.out=(float*)d_out;
  P.N=N; P.E=E; P.nbk=nbk; P.nvb=(N+255)/256;
  int off=0;
  for (int i=0;i<LL;i++){
    P.wfnt[i]=4; P.wfnc[i]=HH; P.wfoff[i]=off;
    off += ((FF+HH*i)>>5)*4*512;
  }
  P.wfnt[LL]=3; P.wfnc[LL]=CC; P.wfoff[LL]=off;
  off += (XDIM>>5)*3*512;
  P.wfoff[LL+1]=off;

  // query cooperative co-residency capacity (host-side, deterministic, capture-safe)
  int blocksPerCU = 0;
  hipError_t oe = hipOccupancyMaxActiveBlocksPerMultiprocessor(&blocksPerCU, k_mega, 256, 0);
  int numCU = 0;
  hipDeviceGetAttribute(&numCU, hipDeviceAttributeMultiprocessorCount, 0);
  int cap = (oe == hipSuccess && blocksPerCU > 0 && numCU > 0) ? blocksPerCU*numCU : 0;
  int Gneed = (N+127)/128;
  int G = (cap > 0) ? (Gneed < cap ? Gneed : cap) : 0;

  hipError_t err = hipErrorUnknown;
  if (G > 0){
    void* args[] = { &P };
    err = hipLaunchCooperativeKernel((const void*)k_mega, dim3(G), dim3(256), args, 0, stream);
  }
  if (err != hipSuccess){
    (void)hipGetLastError();  // clear error state
    // -------- fallback: proven multi-kernel pipeline --------
    hipMemsetAsync(cnt, 0, (size_t)N*4, stream);
    int nb = (N+255)/256;
    k_count<<<2048, 256, 0, stream>>>(ei, E, cnt);
    k_scan1<<<nb, 256, 0, stream>>>(cnt, offs, bsum, dinv, N);
    k_scan2<<<1, 512, 0, stream>>>(bsum, nb);
    k_scan3<<<nb, 256, 0, stream>>>(offs, bsum, bcur, N, E);
    k_bfill<<<2048, 256, 0, stream>>>(ei, E, bcur, tmp);
    k_scatter<<<nbk, 256, 0, stream>>>(tmp, offs, esrc, N);
    k_xcast<<<(N*(FF/4)+255)/256, 256, 0, stream>>>(x, X, lin, N);
    WfA A;
    for (int i=0;i<=LL;i++){ A.W[i]=P.W[i]; A.dst[i]=WfL[i]; A.nt[i]=P.wfnt[i]; A.nc[i]=P.wfnc[i]; A.off[i]=P.wfoff[i]; }
    A.off[LL+1]=P.wfoff[LL+1];
    k_wfrag<<<(A.off[LL+1]+255)/256, 256, 0, stream>>>(A);
    int gb = (N+127)/128;
    int ab = (N+3)/4;
    for (int i=0;i<LL;i++){
      k_gemm<<<gb,256,0,stream>>>(X, WfL[i], dinv, lin, N, (FF+HH*i)>>5);
      k_agg <<<ab,256,0,stream>>>(lin, offs, esrc, dinv, P.bias[i], X, FF+HH*i, N);
    }
    k_final<<<(N+63)/64,256,0,stream>>>(X, WfL[LL], P.bias[LL], (float*)d_out, N);
  }
}

// Round 8
// 788.180 us; speedup vs baseline: 3.0914x; 3.0914x over previous
//
#include <hip/hip_runtime.h>
#include <hip/hip_bf16.h>

#define HH 64
#define XDIM 896
#define FF 512
#define LL 6
#define CC 40

typedef __bf16 bf16x8 __attribute__((ext_vector_type(8)));
typedef float f32x4 __attribute__((ext_vector_type(4)));

__device__ __forceinline__ float bf2f(unsigned short u){
  union{unsigned int u; float f;} v; v.u = ((unsigned int)u)<<16; return v.f;
}
__device__ __forceinline__ unsigned short f2bf(float f){
  union{float f; unsigned int u;} v; v.f=f; unsigned int u=v.u;
  return (unsigned short)((u + 0x7fffu + ((u>>16)&1u))>>16);
}
__device__ __forceinline__ float u2f(unsigned u){
  union{unsigned u; float f;} v; v.u=u; return v.f;
}

// ---- degree count ----
__global__ void __launch_bounds__(256) k_count(const int* __restrict__ ei, int E, int* __restrict__ cnt){
  int i = blockIdx.x*blockDim.x + threadIdx.x;
  int stride = gridDim.x*blockDim.x;
  for (; i < E; i += stride) atomicAdd(&cnt[ei[E+i]], 1);
}

// ---- scan phase 1 (+ dinv fused) ----
__global__ void __launch_bounds__(256) k_scan1(const int* __restrict__ cnt, int* __restrict__ offs,
                                               int* __restrict__ bsum, float* __restrict__ dinv, int N){
  __shared__ int s[256];
  int t=threadIdx.x, gid=blockIdx.x*256+t;
  int v = (gid<N)? cnt[gid] : 0;
  if (gid<N) dinv[gid] = rsqrtf((float)(v+1));
  s[t]=v; __syncthreads();
  for (int o=1;o<256;o<<=1){ int x=(t>=o)?s[t-o]:0; __syncthreads(); s[t]+=x; __syncthreads(); }
  if (gid<N) offs[gid]=s[t]-v;
  if (t==255) bsum[blockIdx.x]=s[t];
}

__global__ void __launch_bounds__(512) k_scan2(int* __restrict__ bsum, int nb){
  __shared__ int s[512];
  int t=threadIdx.x;
  int v=(t<nb)?bsum[t]:0; s[t]=v; __syncthreads();
  for(int o=1;o<512;o<<=1){ int x=(t>=o)?s[t-o]:0; __syncthreads(); s[t]+=x; __syncthreads(); }
  if (t<nb) bsum[t]=s[t]-v;
}

// ---- scan phase 3 (+ bucket cursor init fused; cursors PADDED 1-per-64B-line) ----
__global__ void __launch_bounds__(256) k_scan3(int* __restrict__ offs, const int* __restrict__ bsum,
                                               int* __restrict__ bcur, int N, int E){
  int gid=blockIdx.x*256+threadIdx.x;
  if (gid<N){
    int o=offs[gid]+bsum[gid>>8];
    offs[gid]=o;
    if ((gid&15)==0) bcur[(gid>>4)*16]=o;   // padded: one cursor per cache line
  }
  if (gid==0) offs[N]=E;
}

// ---- pass B: bucket-partition edges (bucket = 16 nodes); padded cursors ----
__global__ void __launch_bounds__(256) k_bfill(const int* __restrict__ ei, int E,
                                               int* __restrict__ bcur, unsigned* __restrict__ tmp){
  int i = blockIdx.x*blockDim.x + threadIdx.x;
  int stride = gridDim.x*blockDim.x;
  for (; i<E; i+=stride){
    int r = ei[i], c = ei[E+i];
    int pos = atomicAdd(&bcur[(c>>4)*16], 1);
    tmp[pos] = ((unsigned)r<<4) | (unsigned)(c & 15);
  }
}

// ---- pass C: within-bucket scatter, LDS cursors (block owns its bucket) ----
__global__ void __launch_bounds__(256) k_scatter(const unsigned* __restrict__ tmp,
                                                 const int* __restrict__ offs,
                                                 int* __restrict__ esrc, int N){
  __shared__ int cur[16];
  int b = blockIdx.x;
  int n0 = b*16;
  int n1 = n0+16; if (n1 > N) n1 = N;
  if (threadIdx.x < 16 && n0 + threadIdx.x < n1)
    cur[threadIdx.x] = offs[n0 + threadIdx.x];
  __syncthreads();
  int start = offs[n0], end = offs[n1];
  for (int i = start + threadIdx.x; i < end; i += 256){
    unsigned v = tmp[i];
    int pos = atomicAdd(&cur[v & 15u], 1);
    esrc[pos] = (int)(v >> 4);
  }
}

// ---- x -> bf16 into X[:, 0:512]; also zero lin's row N ----
__global__ void __launch_bounds__(256) k_xcast(const float* __restrict__ x, unsigned short* __restrict__ X,
                                               unsigned short* __restrict__ lin, int N){
  int i = blockIdx.x*blockDim.x + threadIdx.x;
  if (i < 32) ((unsigned*)(lin + (size_t)N*64))[i] = 0u;
  int total = N*(FF/4);
  if (i >= total) return;
  int row = i/(FF/4), c4 = (i%(FF/4))*4;
  float4 v = *(const float4*)(x + (size_t)row*FF + c4);
  ushort4 o; o.x=f2bf(v.x); o.y=f2bf(v.y); o.z=f2bf(v.z); o.w=f2bf(v.w);
  *(ushort4*)(X + (size_t)row*XDIM + c4) = o;
}

// ---- all W (fp32 [d][ncols]) -> bf16 MFMA B-fragment layout, one launch ----
struct WfA {
  const float* W[7];
  unsigned short* dst[7];
  int nt[7], nc[7];
  int off[8];
};
__global__ void __launch_bounds__(256) k_wfrag(WfA A){
  int idx = blockIdx.x*256 + threadIdx.x;
  if (idx >= A.off[7]) return;
  int seg = 0;
  while (idx >= A.off[seg+1]) ++seg;
  int li = idx - A.off[seg];
  int j = li&7, lane=(li>>3)&63, rem=li>>9;
  int ntile = A.nt[seg], ncols = A.nc[seg];
  int nt = rem % ntile, kb = rem / ntile;
  int k = kb*32 + (lane>>4)*8 + j;
  int c = nt*16 + (lane&15);
  float v = (c<ncols)? A.W[seg][(size_t)k*ncols + c] : 0.f;
  A.dst[seg][li]=f2bf(v);
}

// ---- lin[N,64] = (X[:, :32*nkb] @ Wf) * dinv[row] ; 4 waves/block, 32 rows/wave ----
__global__ void __launch_bounds__(256) k_gemm(const unsigned short* __restrict__ X,
                                              const unsigned short* __restrict__ Wf,
                                              const float* __restrict__ dinv,
                                              unsigned short* __restrict__ lin,
                                              int N, int nkb){
  int lane = threadIdx.x & 63, wid = threadIdx.x >> 6;
  long row0 = (long)blockIdx.x*128 + wid*32;
  int arow = lane & 15, kgrp = lane >> 4;
  long r0 = row0 + arow;      if (r0 > (long)N-1) r0 = N-1;
  long r1 = row0 + 16 + arow; if (r1 > (long)N-1) r1 = N-1;
  const unsigned short* ap0 = X + (size_t)r0*XDIM + kgrp*8;
  const unsigned short* ap1 = X + (size_t)r1*XDIM + kgrp*8;
  const unsigned short* bptr = Wf + lane*8;
  f32x4 acc00={0.f,0.f,0.f,0.f}, acc01=acc00, acc02=acc00, acc03=acc00;
  f32x4 acc10=acc00, acc11=acc00, acc12=acc00, acc13=acc00;
  for (int kb=0; kb<nkb; ++kb){
    bf16x8 a0 = *(const bf16x8*)(ap0 + (size_t)kb*32);
    bf16x8 a1 = *(const bf16x8*)(ap1 + (size_t)kb*32);
    const unsigned short* bp = bptr + (size_t)kb*2048;
    bf16x8 b0=*(const bf16x8*)bp, b1=*(const bf16x8*)(bp+512),
           b2=*(const bf16x8*)(bp+1024), b3=*(const bf16x8*)(bp+1536);
    acc00=__builtin_amdgcn_mfma_f32_16x16x32_bf16(a0,b0,acc00,0,0,0);
    acc10=__builtin_amdgcn_mfma_f32_16x16x32_bf16(a1,b0,acc10,0,0,0);
    acc01=__builtin_amdgcn_mfma_f32_16x16x32_bf16(a0,b1,acc01,0,0,0);
    acc11=__builtin_amdgcn_mfma_f32_16x16x32_bf16(a1,b1,acc11,0,0,0);
    acc02=__builtin_amdgcn_mfma_f32_16x16x32_bf16(a0,b2,acc02,0,0,0);
    acc12=__builtin_amdgcn_mfma_f32_16x16x32_bf16(a1,b2,acc12,0,0,0);
    acc03=__builtin_amdgcn_mfma_f32_16x16x32_bf16(a0,b3,acc03,0,0,0);
    acc13=__builtin_amdgcn_mfma_f32_16x16x32_bf16(a1,b3,acc13,0,0,0);
  }
  for (int j=0;j<4;++j){
    long rr = row0 + kgrp*4 + j;
    if (rr < N){
      float dv = dinv[rr];
      unsigned short* lp = lin + (size_t)rr*64 + arow;
      lp[0]  = f2bf(acc00[j]*dv);
      lp[16] = f2bf(acc01[j]*dv);
      lp[32] = f2bf(acc02[j]*dv);
      lp[48] = f2bf(acc03[j]*dv);
    }
    long rr1 = rr + 16;
    if (rr1 < N){
      float dv = dinv[rr1];
      unsigned short* lp = lin + (size_t)rr1*64 + arow;
      lp[0]  = f2bf(acc10[j]*dv);
      lp[16] = f2bf(acc11[j]*dv);
      lp[32] = f2bf(acc12[j]*dv);
      lp[48] = f2bf(acc13[j]*dv);
    }
  }
}

// ---- aggregate: 1 wave/node; lane=(sub 0..1, fq 0..31); 4B gathers, 2 edges/instr ----
// (layout numerically validated by the R7 mega kernel)
#define AGG_GRP(NG, MASKED, REM) \
  _Pragma("unroll") \
  for (int k=0;k<NG;++k){ \
    int idx = 2*k + sub; \
    int sx = esrc[base + idx]; \
    if (MASKED) sx = (idx < (REM)) ? sx : N; \
    unsigned vv = *(const unsigned*)(lq2 + (size_t)sx*64); \
    a0 += u2f(vv<<16); a1 += u2f(vv & 0xffff0000u); \
  }

__global__ void __launch_bounds__(256) k_agg(const unsigned short* __restrict__ lin,
                                             const int* __restrict__ offs,
                                             const int* __restrict__ esrc,
                                             const float* __restrict__ dinv,
                                             const float* __restrict__ bias,
                                             unsigned short* __restrict__ X,
                                             int colbase, int N){
  int lane = threadIdx.x & 63, wid = threadIdx.x >> 6;
  int n = blockIdx.x*4 + wid;
  if (n >= N) return;
  int sub = lane >> 5;        // edge slot 0..1
  int fq  = lane & 31;        // feature pair
  const unsigned short* lq2 = lin + fq*2;
  float a0=0.f, a1=0.f;
  int s = offs[n], e = offs[n+1];
  int base = s;
  for (; base + 32 <= e; base += 32){ AGG_GRP(16, false, 0) }
  if (base < e){
    int rem = e - base;       // 1..31
    if (rem <= 8)       { AGG_GRP(4,  true, rem) }
    else if (rem <= 16) { AGG_GRP(8,  true, rem) }
    else                { AGG_GRP(16, true, rem) }
  }
  a0 += __shfl_xor(a0,32,64);
  a1 += __shfl_xor(a1,32,64);
  // self-loop (added once)
  unsigned vs = *(const unsigned*)(lq2 + (size_t)n*64);
  a0 += u2f(vs<<16); a1 += u2f(vs&0xffff0000u);
  float dv = dinv[n];
  float2 b2 = *(const float2*)(bias + fq*2);
  float h0 = fmaxf(a0*dv + b2.x, 0.f);
  float h1 = fmaxf(a1*dv + b2.y, 0.f);
  if (sub == 0){
    ushort2 o; o.x=f2bf(h0); o.y=f2bf(h1);
    *(ushort2*)(X + (size_t)n*XDIM + colbase + fq*2) = o;
  }
}

// ---- final: logits = X @ Wlin + blin, log_softmax, write fp32 [N,40] ----
__global__ void __launch_bounds__(256) k_final(const unsigned short* __restrict__ X,
                                               const unsigned short* __restrict__ Wf,
                                               const float* __restrict__ blin,
                                               float* __restrict__ out, int N){
  int lane=threadIdx.x&63, wid=threadIdx.x>>6;
  long row0=(long)blockIdx.x*64 + wid*16;
  int c0=lane&15, g=lane>>4;
  long r=row0+c0; if (r > (long)N-1) r = N-1;
  const unsigned short* aptr = X + (size_t)r*XDIM + g*8;
  const unsigned short* bptr = Wf + lane*8;
  f32x4 acc0={0.f,0.f,0.f,0.f}, acc1=acc0, acc2=acc0;
  const int nkb = XDIM/32;
  for (int kb=0;kb<nkb;++kb){
    bf16x8 a=*(const bf16x8*)(aptr+(size_t)kb*32);
    const unsigned short* bp = bptr + (size_t)kb*1536;
    bf16x8 b0=*(const bf16x8*)bp, b1=*(const bf16x8*)(bp+512), b2=*(const bf16x8*)(bp+1024);
    acc0=__builtin_amdgcn_mfma_f32_16x16x32_bf16(a,b0,acc0,0,0,0);
    acc1=__builtin_amdgcn_mfma_f32_16x16x32_bf16(a,b1,acc1,0,0,0);
    acc2=__builtin_amdgcn_mfma_f32_16x16x32_bf16(a,b2,acc2,0,0,0);
  }
  float bl0 = blin[c0], bl1 = blin[16+c0];
  bool v2ok = (c0 < 8);
  float bl2 = v2ok ? blin[32+c0] : 0.f;
  for (int j=0;j<4;++j){
    long rr = row0 + g*4 + j;
    float v0 = acc0[j]+bl0, v1 = acc1[j]+bl1;
    float v2 = v2ok ? (acc2[j]+bl2) : -1e30f;
    float m = fmaxf(fmaxf(v0,v1),v2);
    m = fmaxf(m, __shfl_xor(m,1,64));
    m = fmaxf(m, __shfl_xor(m,2,64));
    m = fmaxf(m, __shfl_xor(m,4,64));
    m = fmaxf(m, __shfl_xor(m,8,64));
    float sEx = expf(v0-m)+expf(v1-m)+(v2ok?expf(v2-m):0.f);
    sEx += __shfl_xor(sEx,1,64);
    sEx += __shfl_xor(sEx,2,64);
    sEx += __shfl_xor(sEx,4,64);
    sEx += __shfl_xor(sEx,8,64);
    float lse = m + logf(sEx);
    if (rr < N){
      out[(size_t)rr*CC + c0]      = v0 - lse;
      out[(size_t)rr*CC + 16 + c0] = v1 - lse;
      if (v2ok) out[(size_t)rr*CC + 32 + c0] = v2 - lse;
    }
  }
}

extern "C" void kernel_launch(void* const* d_in, const int* in_sizes, int n_in,
                              void* d_out, int out_size, void* d_ws, size_t ws_size,
                              hipStream_t stream){
  const float* x = (const float*)d_in[0];
  const int* ei = (const int*)d_in[1];
  const float* Wl[LL]; const float* bl[LL];
  for (int i=0;i<LL;i++){ Wl[i]=(const float*)d_in[2+2*i]; bl[i]=(const float*)d_in[3+2*i]; }
  const float* Wlin = (const float*)d_in[2+2*LL];
  const float* blin = (const float*)d_in[3+2*LL];
  float* out = (float*)d_out;
  const int N = in_sizes[0]/FF;
  const int E = in_sizes[1]/2;
  const int nbk = (N+15)/16;

  char* p = (char*)d_ws;
  auto alloc = [&](size_t bb)->char*{ char* r=p; p += (bb+255)&~(size_t)255; return r; };
  unsigned short* X   = (unsigned short*)alloc((size_t)N*XDIM*2);
  unsigned short* lin = (unsigned short*)alloc((size_t)(N+1)*64*2);  // +1 zero row
  unsigned* tmp = (unsigned*)lin;  // alias: tmp (E*4B) used only before GEMM phase
  unsigned short* WfL[LL+1];
  for (int i=0;i<LL;i++){ int d=FF+HH*i; WfL[i]=(unsigned short*)alloc((size_t)d*64*2); }
  WfL[LL] = (unsigned short*)alloc((size_t)XDIM*48*2);
  float* dinv = (float*)alloc((size_t)N*4);
  int* cnt    = (int*)alloc((size_t)N*4);
  int* offs   = (int*)alloc((size_t)(N+1)*4);
  int* bcur   = (int*)alloc((size_t)nbk*16*4);   // padded: 1 cursor / 64B line
  int* bsum   = (int*)alloc(512*4);
  int* esrc   = (int*)alloc((size_t)(E+64)*4);   // pad for masked tail reads

  hipMemsetAsync(cnt, 0, (size_t)N*4, stream);

  int nb = (N+255)/256;
  k_count<<<2048, 256, 0, stream>>>(ei, E, cnt);
  k_scan1<<<nb, 256, 0, stream>>>(cnt, offs, bsum, dinv, N);
  k_scan2<<<1, 512, 0, stream>>>(bsum, nb);
  k_scan3<<<nb, 256, 0, stream>>>(offs, bsum, bcur, N, E);
  k_bfill<<<2048, 256, 0, stream>>>(ei, E, bcur, tmp);
  k_scatter<<<nbk, 256, 0, stream>>>(tmp, offs, esrc, N);
  k_xcast<<<(N*(FF/4)+255)/256, 256, 0, stream>>>(x, X, lin, N);

  WfA A;
  int off = 0;
  for (int i=0;i<LL;i++){
    A.W[i]=Wl[i]; A.dst[i]=WfL[i]; A.nt[i]=4; A.nc[i]=HH;
    A.off[i]=off; off += ((FF+HH*i)>>5)*4*512;
  }
  A.W[LL]=Wlin; A.dst[LL]=WfL[LL]; A.nt[LL]=3; A.nc[LL]=CC;
  A.off[LL]=off; off += (XDIM>>5)*3*512;
  A.off[LL+1]=off;
  k_wfrag<<<(off+255)/256, 256, 0, stream>>>(A);

  int gb = (N+127)/128;
  int ab = (N+3)/4;
  for (int i=0;i<LL;i++){
    k_gemm<<<gb,256,0,stream>>>(X, WfL[i], dinv, lin, N, (FF+HH*i)>>5);
    k_agg <<<ab,256,0,stream>>>(lin, offs, esrc, dinv, bl[i], X, FF+HH*i, N);
  }
  k_final<<<(N+63)/64,256,0,stream>>>(X, WfL[LL], blin, out, N);
}

// Round 9
// 608.905 us; speedup vs baseline: 4.0016x; 1.2944x over previous
//
#include <hip/hip_runtime.h>
#include <hip/hip_bf16.h>

#define HH 64
#define XDIM 896
#define FF 512
#define LL 6
#define CC 40
#define CBSZ 512          // nodes per coarse bucket
#define SLACK 10240       // slots per bucket region (mean 8163, +23 sigma)

typedef __bf16 bf16x8 __attribute__((ext_vector_type(8)));
typedef float f32x4 __attribute__((ext_vector_type(4)));

__device__ __forceinline__ unsigned short f2bf(float f){
  union{float f; unsigned int u;} v; v.f=f; unsigned int u=v.u;
  return (unsigned short)((u + 0x7fffu + ((u>>16)&1u))>>16);
}
__device__ __forceinline__ float u2f(unsigned u){
  union{unsigned u; float f;} v; v.u=u; return v.f;
}

// ---- x -> bf16 into X[:, 0:512]; zero lin row N; init bucket cursors ----
__global__ void __launch_bounds__(256) k_xcast(const float* __restrict__ x, unsigned short* __restrict__ X,
                                               unsigned short* __restrict__ lin, int* __restrict__ bcur,
                                               int N, int NB){
  int i = blockIdx.x*blockDim.x + threadIdx.x;
  if (i < 32) ((unsigned*)(lin + (size_t)N*64))[i] = 0u;
  if (i < NB) bcur[i] = i*SLACK;
  int total = N*(FF/4);
  if (i >= total) return;
  int row = i/(FF/4), c4 = (i%(FF/4))*4;
  float4 v = *(const float4*)(x + (size_t)row*FF + c4);
  ushort4 o; o.x=f2bf(v.x); o.y=f2bf(v.y); o.z=f2bf(v.z); o.w=f2bf(v.w);
  *(ushort4*)(X + (size_t)row*XDIM + c4) = o;
}

// ---- all W (fp32 [d][ncols]) -> bf16 MFMA B-fragment layout, one launch ----
struct WfA {
  const float* W[7];
  unsigned short* dst[7];
  int nt[7], nc[7];
  int off[8];
};
__global__ void __launch_bounds__(256) k_wfrag(WfA A){
  int idx = blockIdx.x*256 + threadIdx.x;
  if (idx >= A.off[7]) return;
  int seg = 0;
  while (idx >= A.off[seg+1]) ++seg;
  int li = idx - A.off[seg];
  int j = li&7, lane=(li>>3)&63, rem=li>>9;
  int ntile = A.nt[seg], ncols = A.nc[seg];
  int nt = rem % ntile, kb = rem / ntile;
  int k = kb*32 + (lane>>4)*8 + j;
  int c = nt*16 + (lane&15);
  float v = (c<ncols)? A.W[seg][(size_t)k*ncols + c] : 0.f;
  A.dst[seg][li]=f2bf(v);
}

// ---- partition edges into coarse buckets; LDS hist + bulk reservation + dense writes ----
__global__ void __launch_bounds__(256) k_part(const int* __restrict__ ei, int E, int CH, int NB,
                                              int* __restrict__ bcur, unsigned* __restrict__ tmp){
  __shared__ int hist[256];
  __shared__ int run[256];
  int t=threadIdx.x, b=blockIdx.x;
  int lo=b*CH, hi=lo+CH; if (hi>E) hi=E;
  for (int i=t;i<NB;i+=256) hist[i]=0;
  __syncthreads();
  for (int i=lo+t;i<hi;i+=256) atomicAdd(&hist[ei[E+i]>>9], 1);
  __syncthreads();
  for (int i=t;i<NB;i+=256) run[i]=atomicAdd(&bcur[i], hist[i]);
  __syncthreads();
  for (int i=lo+t;i<hi;i+=256){
    int r=ei[i], c=ei[E+i];
    int pos=atomicAdd(&run[c>>9],1);
    tmp[pos]=((unsigned)r<<9)|(unsigned)(c&(CBSZ-1));
  }
}

// ---- per-bucket: LDS count + scan -> offs/dinv; LDS-cursor scatter -> esrc ----
__global__ void __launch_bounds__(1024) k_build(const unsigned* __restrict__ tmp,
                                                const int* __restrict__ bcur,
                                                int* __restrict__ offsS, int* __restrict__ offsE,
                                                float* __restrict__ dinv,
                                                int* __restrict__ esrc, int N){
  __shared__ int cnt[CBSZ];
  __shared__ int run[CBSZ];
  int t=threadIdx.x, b=blockIdx.x;
  int n0=b*CBSZ;
  int nloc=N-n0; if (nloc>CBSZ) nloc=CBSZ;
  int wbase=b*SLACK;
  int wend=bcur[b];                 // = wbase + bucket length (post k_part)
  if (t<CBSZ) cnt[t]=0;
  __syncthreads();
  for (int i=wbase+t; i<wend; i+=1024) atomicAdd(&cnt[tmp[i]&(CBSZ-1u)],1);
  __syncthreads();
  int v = (t<CBSZ)? cnt[t] : 0;
  if (t<CBSZ) run[t]=v;
  __syncthreads();
  for (int o=1;o<CBSZ;o<<=1){
    int xx = (t<CBSZ && t>=o)? run[t-o] : 0;
    __syncthreads();
    if (t<CBSZ) run[t]+=xx;
    __syncthreads();
  }
  if (t<nloc){
    int s = wbase + (run[t]-v);     // exclusive scan + region base
    offsS[n0+t]=s;
    offsE[n0+t]=s+v;
    dinv[n0+t]=rsqrtf((float)(v+1));
    run[t]=s;                        // becomes the scatter cursor
  }
  __syncthreads();
  for (int i=wbase+t; i<wend; i+=1024){
    unsigned vv=tmp[i];
    int pos=atomicAdd(&run[vv&(CBSZ-1u)],1);
    esrc[pos]=(int)(vv>>9);
  }
}

// ---- lin[N,64] = (X[:, :32*nkb] @ Wf) * dinv[row] ; 4 waves/block, 32 rows/wave ----
__global__ void __launch_bounds__(256) k_gemm(const unsigned short* __restrict__ X,
                                              const unsigned short* __restrict__ Wf,
                                              const float* __restrict__ dinv,
                                              unsigned short* __restrict__ lin,
                                              int N, int nkb){
  int lane = threadIdx.x & 63, wid = threadIdx.x >> 6;
  long row0 = (long)blockIdx.x*128 + wid*32;
  int arow = lane & 15, kgrp = lane >> 4;
  long r0 = row0 + arow;      if (r0 > (long)N-1) r0 = N-1;
  long r1 = row0 + 16 + arow; if (r1 > (long)N-1) r1 = N-1;
  const unsigned short* ap0 = X + (size_t)r0*XDIM + kgrp*8;
  const unsigned short* ap1 = X + (size_t)r1*XDIM + kgrp*8;
  const unsigned short* bptr = Wf + lane*8;
  f32x4 acc00={0.f,0.f,0.f,0.f}, acc01=acc00, acc02=acc00, acc03=acc00;
  f32x4 acc10=acc00, acc11=acc00, acc12=acc00, acc13=acc00;
  for (int kb=0; kb<nkb; ++kb){
    bf16x8 a0 = *(const bf16x8*)(ap0 + (size_t)kb*32);
    bf16x8 a1 = *(const bf16x8*)(ap1 + (size_t)kb*32);
    const unsigned short* bp = bptr + (size_t)kb*2048;
    bf16x8 b0=*(const bf16x8*)bp, b1=*(const bf16x8*)(bp+512),
           b2=*(const bf16x8*)(bp+1024), b3=*(const bf16x8*)(bp+1536);
    acc00=__builtin_amdgcn_mfma_f32_16x16x32_bf16(a0,b0,acc00,0,0,0);
    acc10=__builtin_amdgcn_mfma_f32_16x16x32_bf16(a1,b0,acc10,0,0,0);
    acc01=__builtin_amdgcn_mfma_f32_16x16x32_bf16(a0,b1,acc01,0,0,0);
    acc11=__builtin_amdgcn_mfma_f32_16x16x32_bf16(a1,b1,acc11,0,0,0);
    acc02=__builtin_amdgcn_mfma_f32_16x16x32_bf16(a0,b2,acc02,0,0,0);
    acc12=__builtin_amdgcn_mfma_f32_16x16x32_bf16(a1,b2,acc12,0,0,0);
    acc03=__builtin_amdgcn_mfma_f32_16x16x32_bf16(a0,b3,acc03,0,0,0);
    acc13=__builtin_amdgcn_mfma_f32_16x16x32_bf16(a1,b3,acc13,0,0,0);
  }
  for (int j=0;j<4;++j){
    long rr = row0 + kgrp*4 + j;
    if (rr < N){
      float dv = dinv[rr];
      unsigned short* lp = lin + (size_t)rr*64 + arow;
      lp[0]  = f2bf(acc00[j]*dv);
      lp[16] = f2bf(acc01[j]*dv);
      lp[32] = f2bf(acc02[j]*dv);
      lp[48] = f2bf(acc03[j]*dv);
    }
    long rr1 = rr + 16;
    if (rr1 < N){
      float dv = dinv[rr1];
      unsigned short* lp = lin + (size_t)rr1*64 + arow;
      lp[0]  = f2bf(acc10[j]*dv);
      lp[16] = f2bf(acc11[j]*dv);
      lp[32] = f2bf(acc12[j]*dv);
      lp[48] = f2bf(acc13[j]*dv);
    }
  }
}

// ---- aggregate (R5-proven): 1 wave/node; lane=(sub 0..3, fq 0..15); uint2 gathers ----
__global__ void __launch_bounds__(256) k_agg(const unsigned short* __restrict__ lin,
                                             const int* __restrict__ offsS,
                                             const int* __restrict__ offsE,
                                             const int* __restrict__ esrc,
                                             const float* __restrict__ dinv,
                                             const float* __restrict__ bias,
                                             unsigned short* __restrict__ X,
                                             int colbase, int N){
  int lane = threadIdx.x & 63, wid = threadIdx.x >> 6;
  int n = blockIdx.x*4 + wid;
  if (n >= N) return;
  int sub = lane >> 4;
  int fq  = lane & 15;
  const unsigned short* lq = lin + fq*4;
  float a0=0.f, a1=0.f, a2=0.f, a3=0.f;
  int s = offsS[n], e = offsE[n];
  int base = s;
  for (; base + 32 <= e; base += 32){
    #pragma unroll
    for (int k=0;k<8;++k){
      int sx = esrc[base + 4*k + sub];
      uint2 v = *(const uint2*)(lq + (size_t)sx*64);
      a0 += u2f(v.x<<16); a1 += u2f(v.x&0xffff0000u);
      a2 += u2f(v.y<<16); a3 += u2f(v.y&0xffff0000u);
    }
  }
  if (base < e){
    int rem = e - base;
    if (rem > 16){
      #pragma unroll
      for (int k=0;k<8;++k){
        int idx = 4*k + sub;
        int sx = esrc[base + idx];
        sx = (idx < rem) ? sx : (int)N;
        uint2 v = *(const uint2*)(lq + (size_t)sx*64);
        a0 += u2f(v.x<<16); a1 += u2f(v.x&0xffff0000u);
        a2 += u2f(v.y<<16); a3 += u2f(v.y&0xffff0000u);
      }
    } else {
      #pragma unroll
      for (int k=0;k<4;++k){
        int idx = 4*k + sub;
        int sx = esrc[base + idx];
        sx = (idx < rem) ? sx : (int)N;
        uint2 v = *(const uint2*)(lq + (size_t)sx*64);
        a0 += u2f(v.x<<16); a1 += u2f(v.x&0xffff0000u);
        a2 += u2f(v.y<<16); a3 += u2f(v.y&0xffff0000u);
      }
    }
  }
  a0 += __shfl_xor(a0,16,64); a0 += __shfl_xor(a0,32,64);
  a1 += __shfl_xor(a1,16,64); a1 += __shfl_xor(a1,32,64);
  a2 += __shfl_xor(a2,16,64); a2 += __shfl_xor(a2,32,64);
  a3 += __shfl_xor(a3,16,64); a3 += __shfl_xor(a3,32,64);
  uint2 vs = *(const uint2*)(lq + (size_t)n*64);
  a0 += u2f(vs.x<<16); a1 += u2f(vs.x&0xffff0000u);
  a2 += u2f(vs.y<<16); a3 += u2f(vs.y&0xffff0000u);
  float dv = dinv[n];
  float4 b4 = *(const float4*)(bias + fq*4);
  float h0 = fmaxf(a0*dv + b4.x, 0.f);
  float h1 = fmaxf(a1*dv + b4.y, 0.f);
  float h2 = fmaxf(a2*dv + b4.z, 0.f);
  float h3 = fmaxf(a3*dv + b4.w, 0.f);
  if (sub == 0){
    ushort4 o; o.x=f2bf(h0); o.y=f2bf(h1); o.z=f2bf(h2); o.w=f2bf(h3);
    *(ushort4*)(X + (size_t)n*XDIM + colbase + fq*4) = o;
  }
}

// ---- final: logits = X @ Wlin + blin, log_softmax, write fp32 [N,40] ----
__global__ void __launch_bounds__(256) k_final(const unsigned short* __restrict__ X,
                                               const unsigned short* __restrict__ Wf,
                                               const float* __restrict__ blin,
                                               float* __restrict__ out, int N){
  int lane=threadIdx.x&63, wid=threadIdx.x>>6;
  long row0=(long)blockIdx.x*64 + wid*16;
  int c0=lane&15, g=lane>>4;
  long r=row0+c0; if (r > (long)N-1) r = N-1;
  const unsigned short* aptr = X + (size_t)r*XDIM + g*8;
  const unsigned short* bptr = Wf + lane*8;
  f32x4 acc0={0.f,0.f,0.f,0.f}, acc1=acc0, acc2=acc0;
  const int nkb = XDIM/32;
  for (int kb=0;kb<nkb;++kb){
    bf16x8 a=*(const bf16x8*)(aptr+(size_t)kb*32);
    const unsigned short* bp = bptr + (size_t)kb*1536;
    bf16x8 b0=*(const bf16x8*)bp, b1=*(const bf16x8*)(bp+512), b2=*(const bf16x8*)(bp+1024);
    acc0=__builtin_amdgcn_mfma_f32_16x16x32_bf16(a,b0,acc0,0,0,0);
    acc1=__builtin_amdgcn_mfma_f32_16x16x32_bf16(a,b1,acc1,0,0,0);
    acc2=__builtin_amdgcn_mfma_f32_16x16x32_bf16(a,b2,acc2,0,0,0);
  }
  float bl0 = blin[c0], bl1 = blin[16+c0];
  bool v2ok = (c0 < 8);
  float bl2 = v2ok ? blin[32+c0] : 0.f;
  for (int j=0;j<4;++j){
    long rr = row0 + g*4 + j;
    float v0 = acc0[j]+bl0, v1 = acc1[j]+bl1;
    float v2 = v2ok ? (acc2[j]+bl2) : -1e30f;
    float m = fmaxf(fmaxf(v0,v1),v2);
    m = fmaxf(m, __shfl_xor(m,1,64));
    m = fmaxf(m, __shfl_xor(m,2,64));
    m = fmaxf(m, __shfl_xor(m,4,64));
    m = fmaxf(m, __shfl_xor(m,8,64));
    float sEx = expf(v0-m)+expf(v1-m)+(v2ok?expf(v2-m):0.f);
    sEx += __shfl_xor(sEx,1,64);
    sEx += __shfl_xor(sEx,2,64);
    sEx += __shfl_xor(sEx,4,64);
    sEx += __shfl_xor(sEx,8,64);
    float lse = m + logf(sEx);
    if (rr < N){
      out[(size_t)rr*CC + c0]      = v0 - lse;
      out[(size_t)rr*CC + 16 + c0] = v1 - lse;
      if (v2ok) out[(size_t)rr*CC + 32 + c0] = v2 - lse;
    }
  }
}

extern "C" void kernel_launch(void* const* d_in, const int* in_sizes, int n_in,
                              void* d_out, int out_size, void* d_ws, size_t ws_size,
                              hipStream_t stream){
  const float* x = (const float*)d_in[0];
  const int* ei = (const int*)d_in[1];
  const float* Wl[LL]; const float* bl[LL];
  for (int i=0;i<LL;i++){ Wl[i]=(const float*)d_in[2+2*i]; bl[i]=(const float*)d_in[3+2*i]; }
  const float* Wlin = (const float*)d_in[2+2*LL];
  const float* blin = (const float*)d_in[3+2*LL];
  float* out = (float*)d_out;
  const int N = in_sizes[0]/FF;
  const int E = in_sizes[1]/2;
  const int NB = (N+CBSZ-1)/CBSZ;   // 196 coarse buckets

  char* p = (char*)d_ws;
  auto alloc = [&](size_t bb)->char*{ char* r=p; p += (bb+255)&~(size_t)255; return r; };
  unsigned short* X   = (unsigned short*)alloc((size_t)N*XDIM*2);
  unsigned short* lin = (unsigned short*)alloc((size_t)(N+1)*64*2);  // +1 zero row
  unsigned* tmp = (unsigned*)lin;  // alias: tmp (NB*SLACK*4 = 8MB <= 12.8MB) dead before gemm
  unsigned short* WfL[LL+1];
  for (int i=0;i<LL;i++){ int d=FF+HH*i; WfL[i]=(unsigned short*)alloc((size_t)d*64*2); }
  WfL[LL] = (unsigned short*)alloc((size_t)XDIM*48*2);
  float* dinv  = (float*)alloc((size_t)N*4);
  int* offsS   = (int*)alloc((size_t)N*4);
  int* offsE   = (int*)alloc((size_t)N*4);
  int* bcur    = (int*)alloc((size_t)NB*4);
  int* esrc    = (int*)alloc((size_t)NB*SLACK*4);

  k_xcast<<<(N*(FF/4)+255)/256, 256, 0, stream>>>(x, X, lin, bcur, N, NB);

  WfA A;
  int off = 0;
  for (int i=0;i<LL;i++){
    A.W[i]=Wl[i]; A.dst[i]=WfL[i]; A.nt[i]=4; A.nc[i]=HH;
    A.off[i]=off; off += ((FF+HH*i)>>5)*4*512;
  }
  A.W[LL]=Wlin; A.dst[LL]=WfL[LL]; A.nt[LL]=3; A.nc[LL]=CC;
  A.off[LL]=off; off += (XDIM>>5)*3*512;
  A.off[LL+1]=off;
  k_wfrag<<<(off+255)/256, 256, 0, stream>>>(A);

  int CH = (E+255)/256;
  k_part <<<256, 256, 0, stream>>>(ei, E, CH, NB, bcur, tmp);
  k_build<<<NB, 1024, 0, stream>>>(tmp, bcur, offsS, offsE, dinv, esrc, N);

  int gb = (N+127)/128;
  int ab = (N+3)/4;
  for (int i=0;i<LL;i++){
    k_gemm<<<gb,256,0,stream>>>(X, WfL[i], dinv, lin, N, (FF+HH*i)>>5);
    k_agg <<<ab,256,0,stream>>>(lin, offsS, offsE, esrc, dinv, bl[i], X, FF+HH*i, N);
  }
  k_final<<<(N+63)/64,256,0,stream>>>(X, WfL[LL], blin, out, N);
}